// Round 10
// baseline (99.245 us; speedup 1.0000x reference)
//
#include <hip/hip_runtime.h>
#include <math.h>

// FlowLevel: DIM=2, half=1 -> per-layer coupling depends on scalar v = z_b.
// t(v) and u(v) (pre-sigmoid) are piecewise-LINEAR in v (ReLU MLP).
// Tabulate (t, dt/dv, u, du/dv) per node; apply reconstructs with two
// tangent lines (exact for <=1 kink per cell).
//
// Build v8: global kink-sorted prefix functions -> O(1) work per node,
// perfect load balance (v7's central tiles were a 40us LDS-bound tail).
//   prep (10 blocks):  per layer, sort the 128 kinks; sweep once to build
//     C_g[p][k], C_b[p][k] = active-set dots for prefix index p (g>0 active
//     = prefix of sorted order, g<0 active = suffix; ties contribute 0).
//     bz folded into C_b. Weights LDS-transposed for coalesced sweep reads.
//   table (2560 blocks): per node: p = #{kinks < v} (LDS broadcast count),
//     raw_k = v*C_g[p][k] + C_b[p][k]  (EXACT), relu + fc3 dot, write.

constexpr int kDepth = 10;
constexpr int kWidth = 128;
constexpr float kVMin = -24.0f;
constexpr float kVMax =  24.0f;

// ---------------- prep: per-layer kink sort + prefix sweep ----------------
__global__ void prep_kernel(
    const float* __restrict__ an_scale,
    const float* __restrict__ conv_w,
    const float* __restrict__ fc1_w, const float* __restrict__ fc1_b,
    const float* __restrict__ an1_scale, const float* __restrict__ an1_bias,
    const float* __restrict__ fc2_w, const float* __restrict__ fc2_b,
    const float* __restrict__ an2_scale, const float* __restrict__ an2_bias,
    const float* __restrict__ fc3_b, const float* __restrict__ lsf,
    float* __restrict__ meta, float* __restrict__ kv,
    float* __restrict__ CG, float* __restrict__ CB)
{
  __shared__ float sWT[128 * 129];           // transposed weights, padded
  __shared__ float sVs[128], sG[128], sB[128], sSig[128];
  __shared__ int   sOrd[128];

  const int l = blockIdx.x;                  // layer
  const int t = threadIdx.x;                 // 0..127 (j, then k)

  // per-j gate params and kink position
  {
    const float s1 = an1_scale[l*kWidth + t];
    const float g = fc1_w[l*kWidth + t] / s1;
    const float b = (fc1_b[l*kWidth + t] - an1_bias[l*kWidth + t]) / s1;
    float vs, sg;
    if (g > 0.0f)      { vs = -b / g; sg =  1.0f; }
    else if (g < 0.0f) { vs = -b / g; sg = -1.0f; }
    else               { vs = (b > 0.0f) ? -1e30f : 1e30f; sg = (b > 0.0f) ? 1.0f : 0.0f; }
    sG[t] = g; sB[t] = b; sVs[t] = vs; sSig[t] = sg;
  }
  __syncthreads();

  // stable rank sort by kink position
  {
    const float my = sVs[t];
    int r = 0;
    for (int i = 0; i < 128; ++i) {
      const float o = sVs[i];
      r += (o < my) || (o == my && i < t);
    }
    sOrd[r] = t;
  }

  // transpose fc2_w (row k over j) into sWT[j][k]
  const float* wl = fc2_w + (size_t)l * kWidth * kWidth;
  for (int k = 0; k < 128; ++k)
    sWT[t * 129 + k] = wl[(size_t)k * kWidth + t];   // coalesced read of row k
  __syncthreads();

  // sorted kink list out (for table kernel's p-count)
  kv[l*128 + t] = sVs[sOrd[t]];

  // base C[0] (thread t owns k=t): all neg-g active, plus folded bz
  float cg = 0.0f;
  float cb = fc2_b[l*kWidth + t] - an2_bias[l*kWidth + t];
  for (int p = 0; p < 128; ++p) {
    const int j = sOrd[p];                   // wave-uniform
    const float g = sG[j];
    if (g < 0.0f) {
      const float w = sWT[j * 129 + t];
      cg = fmaf(g, w, cg);
      cb = fmaf(sB[j], w, cb);
    }
  }

  // sweep: write row p, then cross kink p (pos adds, neg subtracts, dead 0)
  const size_t base = (size_t)l * 129 * 128;
  for (int p = 0; p < 129; ++p) {
    CG[base + (size_t)p * 128 + t] = cg;
    CB[base + (size_t)p * 128 + t] = cb;
    if (p < 128) {
      const int j = sOrd[p];
      const float sg = sSig[j];
      const float w  = sWT[j * 129 + t];
      cg = fmaf(sg * sG[j], w, cg);
      cb = fmaf(sg * sB[j], w, cb);
    }
  }

  // per-layer epilogue constants
  if (t == 0) {
    meta[16 + l*4 + 0] = expf(lsf[l*2 + 0]);
    meta[16 + l*4 + 1] = expf(lsf[l*2 + 1]);
    meta[16 + l*4 + 2] = fc3_b[l*2 + 0];
    meta[16 + l*4 + 3] = fc3_b[l*2 + 1];
  }
  if (l == 0 && t == 0) {
    float cst = 0.0f;
    for (int i = 0; i < kDepth; ++i) {
      cst -= logf(fabsf(an_scale[i*2+0]));
      cst -= logf(fabsf(an_scale[i*2+1]));
      const float* cw = conv_w + i * 4;
      float det = cw[0]*cw[3] - cw[1]*cw[2];
      cst += logf(fabsf(det));   // slogdet(conv)[1]
    }
    meta[0] = cst;
  }
}

// ---------------- table: O(1)-per-node evaluation from prefix arrays ----------------
__global__ __launch_bounds__(256) void table_kernel(
    const float* __restrict__ an2_scale,
    const float* __restrict__ fc3_w,
    const float* __restrict__ meta, const float* __restrict__ kv,
    const float* __restrict__ CG, const float* __restrict__ CB,
    int tabN, float4* __restrict__ tab)
{
  __shared__ float sKz[128], sKw[128], sKv[128];

  const int bpl   = tabN >> 6;
  const int l     = blockIdx.x / bpl;
  const int node0 = (blockIdx.x % bpl) * 64;
  const int t     = threadIdx.x;

  if (t < 128) {
    const float si = 1.0f / an2_scale[l*kWidth + t];
    sKz[t] = fc3_w[l*2*kWidth + t] * si;
    sKw[t] = fc3_w[l*2*kWidth + kWidth + t] * si;
    sKv[t] = kv[l*128 + t];
  }
  __syncthreads();

  const int node = t >> 2, kq = t & 3;
  const float dv = (kVMax - kVMin) / (float)(tabN - 1);
  const float v  = kVMin + dv * (float)(node0 + node);

  // prefix index p = #{kinks < v}
  int p = 0;
  const float4* kv4 = (const float4*)sKv;
#pragma unroll
  for (int m = 0; m < 32; ++m) {
    float4 K = kv4[m];
    p += (K.x < v) + (K.y < v) + (K.z < v) + (K.w < v);
  }

  const float4* cg4 = (const float4*)(CG + ((size_t)l*129 + p) * 128 + kq*32);
  const float4* cb4 = (const float4*)(CB + ((size_t)l*129 + p) * 128 + kq*32);
  const float4* kz4 = (const float4*)sKz + kq*8;
  const float4* kw4 = (const float4*)sKw + kq*8;

  float o0 = 0.f, o1 = 0.f, p0 = 0.f, p1 = 0.f;
#pragma unroll
  for (int c = 0; c < 8; ++c) {
    float4 G = cg4[c], B = cb4[c], Z = kz4[c], W = kw4[c];
    float raw, h, dd;
    raw = fmaf(v, G.x, B.x); h = fmaxf(raw, 0.f); dd = (raw > 0.f) ? G.x : 0.f;
    o0 = fmaf(h, Z.x, o0); o1 = fmaf(h, W.x, o1); p0 = fmaf(dd, Z.x, p0); p1 = fmaf(dd, W.x, p1);
    raw = fmaf(v, G.y, B.y); h = fmaxf(raw, 0.f); dd = (raw > 0.f) ? G.y : 0.f;
    o0 = fmaf(h, Z.y, o0); o1 = fmaf(h, W.y, o1); p0 = fmaf(dd, Z.y, p0); p1 = fmaf(dd, W.y, p1);
    raw = fmaf(v, G.z, B.z); h = fmaxf(raw, 0.f); dd = (raw > 0.f) ? G.z : 0.f;
    o0 = fmaf(h, Z.z, o0); o1 = fmaf(h, W.z, o1); p0 = fmaf(dd, Z.z, p0); p1 = fmaf(dd, W.z, p1);
    raw = fmaf(v, G.w, B.w); h = fmaxf(raw, 0.f); dd = (raw > 0.f) ? G.w : 0.f;
    o0 = fmaf(h, Z.w, o0); o1 = fmaf(h, W.w, o1); p0 = fmaf(dd, Z.w, p0); p1 = fmaf(dd, W.w, p1);
  }

  // reduce over the 4 kq lanes (adjacent in-wave)
  o0 += __shfl_xor(o0, 1); o0 += __shfl_xor(o0, 2);
  o1 += __shfl_xor(o1, 1); o1 += __shfl_xor(o1, 2);
  p0 += __shfl_xor(p0, 1); p0 += __shfl_xor(p0, 2);
  p1 += __shfl_xor(p1, 1); p1 += __shfl_xor(p1, 2);

  if (kq == 0) {
    const float E0  = meta[16 + l*4 + 0];
    const float E1  = meta[16 + l*4 + 1];
    const float b30 = meta[16 + l*4 + 2];
    const float b31 = meta[16 + l*4 + 3];
    tab[(size_t)l * tabN + node0 + node] =
        make_float4((o0 + b30) * E0, p0 * E0, (o1 + b31) * E1, p1 * E1);
  }
}

// ---------------- main: per-sample 10-layer loop with two-line reconstruction ----------------
__global__ __launch_bounds__(256) void flow_apply_kernel(
    const float* __restrict__ x,
    const float* __restrict__ an_scale, const float* __restrict__ an_bias,
    const float* __restrict__ conv_w,
    const float4* __restrict__ tab, const float* __restrict__ extra,
    int tabN,
    float* __restrict__ out_z, float* __restrict__ out_ld, int n)
{
  int idx = blockIdx.x * blockDim.x + threadIdx.x;
  if (idx >= n) return;

  float2 z = reinterpret_cast<const float2*>(x)[idx];
  float ld = extra[0];
  const float dv = (kVMax - kVMin) / (float)(tabN - 1);
  const float inv_dv = (float)(tabN - 1) / (kVMax - kVMin);

#pragma unroll
  for (int i = 0; i < kDepth; ++i) {
    // actnorm
    float za = (z.x - an_bias[i*2+0]) / an_scale[i*2+0];
    float zb = (z.y - an_bias[i*2+1]) / an_scale[i*2+1];
    // 1x1 conv (2x2): z' = W z
    const float* cw = conv_w + i*4;
    float na = fmaf(cw[0], za, cw[1]*zb);
    float nb = fmaf(cw[2], za, cw[3]*zb);
    // table cell
    float xq = (nb - kVMin) * inv_dv;
    int qi = (int)floorf(xq);
    qi = qi < 0 ? 0 : (qi > tabN-2 ? tabN-2 : qi);
    float v0 = fmaf((float)qi, dv, kVMin);
    float v1 = v0 + dv;
    float4 e0 = tab[(size_t)i*tabN + qi];
    float4 e1 = tab[(size_t)i*tabN + qi + 1];
    // two-tangent-line reconstruction (exact for <=1 kink per cell)
    float tL = fmaf(nb - v0, e0.y, e0.x);
    float tR = fmaf(nb - v1, e1.y, e1.x);
    float tt = (e1.y >= e0.y) ? fmaxf(tL, tR) : fminf(tL, tR);
    float uL = fmaf(nb - v0, e0.w, e0.z);
    float uR = fmaf(nb - v1, e1.w, e1.z);
    float uu = (e1.w >= e0.w) ? fmaxf(uL, uR) : fminf(uL, uR);
    // exact sigmoid / log-sigmoid of arg = u + 2
    float arg = uu + 2.0f;
    float e = expf(-arg);
    float s = 1.0f / (1.0f + e);
    float lsv = -logf(1.0f + e);
    // coupling
    z.x = fmaf(s, na, tt);
    z.y = nb;
    ld += lsv;
  }

  reinterpret_cast<float2*>(out_z)[idx] = z;
  out_ld[idx] = ld;
}

extern "C" void kernel_launch(void* const* d_in, const int* in_sizes, int n_in,
                              void* d_out, int out_size, void* d_ws, size_t ws_size,
                              hipStream_t stream) {
  const float* x         = (const float*)d_in[0];
  const float* an_scale  = (const float*)d_in[1];
  const float* an_bias   = (const float*)d_in[2];
  const float* conv_w    = (const float*)d_in[3];
  const float* fc1_w     = (const float*)d_in[4];
  const float* fc1_b     = (const float*)d_in[5];
  const float* an1_scale = (const float*)d_in[6];
  const float* an1_bias  = (const float*)d_in[7];
  const float* fc2_w     = (const float*)d_in[8];
  const float* fc2_b     = (const float*)d_in[9];
  const float* an2_scale = (const float*)d_in[10];
  const float* an2_bias  = (const float*)d_in[11];
  const float* fc3_w     = (const float*)d_in[12];
  const float* fc3_b     = (const float*)d_in[13];
  const float* lsf       = (const float*)d_in[14];

  const int n = in_sizes[0] / 2;

  // ws layout: [meta: 64 f][kv: 10*128 f][CG: 10*129*128 f][CB: same][tab]
  const size_t metaF = 64, kvF = (size_t)kDepth * 128, cF = (size_t)kDepth * 129 * 128;
  const size_t headF = metaF + kvF + 2 * cF;     // floats before tab (16B-aligned)
  int tabN = 16384;
  while (tabN > 2048 &&
         headF * 4 + (size_t)kDepth * tabN * sizeof(float4) > ws_size) {
    tabN >>= 1;
  }
  float* meta = (float*)d_ws;
  float* kv   = meta + metaF;
  float* CG   = kv + kvF;
  float* CB   = CG + cF;
  float4* tab = (float4*)(CB + cF);

  prep_kernel<<<kDepth, 128, 0, stream>>>(
      an_scale, conv_w, fc1_w, fc1_b, an1_scale, an1_bias,
      fc2_w, fc2_b, an2_scale, an2_bias, fc3_b, lsf,
      meta, kv, CG, CB);

  table_kernel<<<kDepth * (tabN / 64), 256, 0, stream>>>(
      an2_scale, fc3_w, meta, kv, CG, CB, tabN, tab);

  float* out_z  = (float*)d_out;
  float* out_ld = out_z + (size_t)2 * n;
  flow_apply_kernel<<<(n + 255) / 256, 256, 0, stream>>>(
      x, an_scale, an_bias, conv_w, tab, meta, tabN, out_z, out_ld, n);
}